// Round 9
// baseline (3611.041 us; speedup 1.0000x reference)
//
#include <hip/hip_runtime.h>
#include <math.h>
#include <stdint.h>

#define VOCAB 2048
#define EMB   512
#define HID   1024
#define TX    256
#define BATCH 64

typedef __attribute__((ext_vector_type(8))) short bf16x8;
typedef __attribute__((ext_vector_type(4))) float f32x4;
typedef unsigned int u32;
typedef unsigned short u16;
typedef unsigned long long u64;
typedef __attribute__((ext_vector_type(4))) u32 u32x4;

// ---------------- ws byte offsets ----------------
// cnt0a/cnt0b/cnt1 : [256 t][4 wave][8 shard] counters, 128B-strided words.
// h0P   : 257 slabs of [128 kblk][64 b][8] bf16
// h1P   : 257 slabs (slab 0 zeroed)
// xP    : [TX][64 kblk][64 b][8] bf16
// WoutP : [128 vt][32 s][2 hl][64 lane] u32x4 (bf16 hi/lo MFMA fragments)
#define OFF_CNT0A 0u
#define OFF_CNT0B 1048576u
#define OFF_CNT1  2097152u
#define OFF_H0    3145728u
#define OFF_H1    36831232u
#define OFF_XP    70516736u
#define OFF_WOUT  87293952u
#define SLAB_U16  65536u
#define SLAB_V4   8192u

__device__ __forceinline__ u16 f2bf(float x){
  u32 v = __float_as_uint(x);
  v += 0x7fffu + ((v >> 16) & 1u);          // RNE
  return (u16)(v >> 16);
}
__device__ __forceinline__ u32 pack2(float a, float b){
  return (u32)f2bf(a) | ((u32)f2bf(b) << 16);
}
__device__ __forceinline__ float bf2f(u16 h){ return __uint_as_float(((u32)h) << 16); }
__device__ __forceinline__ float sigm(float x){ return 1.f/(1.f+__expf(-x)); }
__device__ __forceinline__ float tanh_(float x){
  float e = __expf(2.f*fabsf(x));           // overflow-safe
  return copysignf(1.f - 2.f/(e+1.f), x);
}

// ---------------------------------------------------------------------------
// Prologue: blocks <4096 pack embeddings; blocks >=4096 pack W_out into
// MFMA-fragment-ready bf16 hi/lo pairs (split precision).
// ---------------------------------------------------------------------------
__global__ __launch_bounds__(256) void prologue_pack(
    const int* __restrict__ x, const float* __restrict__ emb,
    const float* __restrict__ W_out,
    u32x4* __restrict__ xP, u32x4* __restrict__ WoutP)
{
  if (blockIdx.x < 4096){
    int flat = blockIdx.x*256 + threadIdx.x;   // t*4096 + kblk*64 + b
    int b    = flat & 63;
    int kblk = (flat >> 6) & 63;
    int t    = flat >> 12;
    int idx  = x[b*TX + t];
    const float* src = emb + (size_t)idx*EMB + kblk*8;
    u32x4 o;
    o.x = pack2(src[0], src[1]);
    o.y = pack2(src[2], src[3]);
    o.z = pack2(src[4], src[5]);
    o.w = pack2(src[6], src[7]);
    xP[flat] = o;
  } else {
    // j = ((vt*32 + s)*2 + hl)*64 + l ; v = vt*16+(l&15), k = s*32+(l>>4)*8
    int j  = (blockIdx.x - 4096)*256 + threadIdx.x;   // [0, 524288)
    int l  = j & 63, hl = (j >> 6) & 1, s = (j >> 7) & 31, vt = j >> 12;
    int v  = vt*16 + (l & 15);
    int k  = s*32 + (l >> 4)*8;
    const float* src = W_out + (size_t)v*HID + k;
    float4 f0 = *(const float4*)src, f1 = *(const float4*)(src + 4);
    float e[8] = {f0.x,f0.y,f0.z,f0.w,f1.x,f1.y,f1.z,f1.w};
    u32x4 o;
    if (hl == 0){
      u16 h0_ = f2bf(e[0]), h1_ = f2bf(e[1]), h2_ = f2bf(e[2]), h3_ = f2bf(e[3]);
      u16 h4_ = f2bf(e[4]), h5_ = f2bf(e[5]), h6_ = f2bf(e[6]), h7_ = f2bf(e[7]);
      o.x = (u32)h0_|((u32)h1_<<16); o.y = (u32)h2_|((u32)h3_<<16);
      o.z = (u32)h4_|((u32)h5_<<16); o.w = (u32)h6_|((u32)h7_<<16);
    } else {
      float lo[8];
      #pragma unroll
      for (int r = 0; r < 8; ++r) lo[r] = e[r] - bf2f(f2bf(e[r]));
      o.x = pack2(lo[0],lo[1]); o.y = pack2(lo[2],lo[3]);
      o.z = pack2(lo[4],lo[5]); o.w = pack2(lo[6],lo[7]);
    }
    WoutP[j] = o;
  }
}

// ---------------------------------------------------------------------------
// Fused persistent kernel. 256 blocks x 512 threads (8 waves), 1 block/CU.
// Waves 0-3: layer-specialized recurrence (identical to round-8 logic).
//   Blocks 0..127 = L1, 128..255 = L2; weights bf16 in LDS; wave-decoupled
//   counters; zero block barriers in the t-loop.
// Waves 4-7: output projection. 1024 out-waves; wave g owns vtile g&127 and
//   timesteps t = (g>>7) + 8i. Polls cnt1(t), reads h1 slab as MFMA A-operand
//   (swapped operands -> D row=batch, col=vocab -> coalesced stores), W_out
//   fragments (hi/lo bf16) straight from global. No LDS use, acyclic waits.
// ---------------------------------------------------------------------------
#define MFMA(ACC, AV, BV)                                                       \
  ACC = __builtin_amdgcn_mfma_f32_16x16x32_bf16(                                \
      *(bf16x8*)&(AV), *(bf16x8*)&(BV), ACC, 0, 0, 0)

__device__ __forceinline__ u32 cell_h(const f32x4& A, const f32x4& B,
                                      const float* bs, float& c){
  float p0=A[0]+B[0]+bs[0], p1=A[1]+B[1]+bs[1];
  float p2=A[2]+B[2]+bs[2], p3=A[3]+B[3]+bs[3];
  float iv=sigm(p0), fv=sigm(p1), gv=tanh_(p2), ov=sigm(p3);
  c = fv*c + iv*gv;
  return (u32)f2bf(ov*tanh_(c));
}

// recurrence wave poll: lanes 0..7 watch 8 shard words of own (t,w) group
__device__ __forceinline__ void pollw(const int* base){
  const int l = threadIdx.x & 63;
  const int* c = base + (l & 7)*32;
  const bool mine = (l < 8);
  for (;;){
    int v = mine ? __hip_atomic_load(c, __ATOMIC_RELAXED, __HIP_MEMORY_SCOPE_AGENT)
                 : 16;
    if (__all(v >= 16)) break;
    __builtin_amdgcn_s_sleep(1);
  }
  asm volatile("" ::: "memory");
}

// out-wave poll: all 32 words (4 wave-groups x 8 shards) of cnt1(t)
__device__ __forceinline__ void pollt(const int* cnt1, int t){
  const int l = threadIdx.x & 63;
  const int* c = cnt1 + (((size_t)t*4 + (l >> 3))*8 + (l & 7))*32;
  const bool mine = (l < 32);
  for (;;){
    int v = mine ? __hip_atomic_load(c, __ATOMIC_RELAXED, __HIP_MEMORY_SCOPE_AGENT)
                 : 16;
    if (__all(v >= 16)) break;
    __builtin_amdgcn_s_sleep(4);
  }
  asm volatile("" ::: "memory");
}

__device__ __forceinline__ void pub_store(u16* dstp, u32 m0, u32 m1){
  const int l = threadIdx.x & 63;
  u32 p = m0 | (m1 << 16);
  int col = l & 15;
  u32 q0 = (u32)__shfl((int)p, col);
  u32 q1 = (u32)__shfl((int)p, col + 16);
  u32 q2 = (u32)__shfl((int)p, col + 32);
  u32 q3 = (u32)__shfl((int)p, col + 48);
  if (l < 16){
    u64 lo = ((u64)((q2 & 0xffffu) | (q3 << 16)) << 32)
           |  (u64)((q0 & 0xffffu) | (q1 << 16));
    u64 hi = ((u64)((q2 >> 16) | (q3 & 0xffff0000u)) << 32)
           |  (u64)((q0 >> 16) | (q1 & 0xffff0000u));
    u64* dst = (u64*)(dstp + (size_t)l*8);
    __hip_atomic_store(dst,     lo, __ATOMIC_RELAXED, __HIP_MEMORY_SCOPE_AGENT);
    __hip_atomic_store(dst + 1, hi, __ATOMIC_RELAXED, __HIP_MEMORY_SCOPE_AGENT);
  }
}

__device__ __forceinline__ void pub_signal(int* add1, int* add2){
  asm volatile("s_waitcnt vmcnt(0)" ::: "memory");   // wave-local drain
  if ((threadIdx.x & 63) == 0){
    __hip_atomic_fetch_add(add1, 1, __ATOMIC_RELAXED, __HIP_MEMORY_SCOPE_AGENT);
    if (add2)
      __hip_atomic_fetch_add(add2, 1, __ATOMIC_RELAXED, __HIP_MEMORY_SCOPE_AGENT);
  }
}

__global__ __launch_bounds__(512, 1) void lstm_persist(
    const u32x4* __restrict__ xP, u16* __restrict__ h0P, u16* __restrict__ h1P,
    const u32x4* __restrict__ WoutP, const float* __restrict__ b_out,
    float* __restrict__ out,
    const float* __restrict__ Wih1, const float* __restrict__ Whh1,
    const float* __restrict__ Wih2, const float* __restrict__ Whh2,
    const float* __restrict__ bi1, const float* __restrict__ bh1,
    const float* __restrict__ bi2, const float* __restrict__ bh2,
    int* __restrict__ cnt0a, int* __restrict__ cnt0b, int* __restrict__ cnt1)
{
  __shared__ u32x4 sW[8192];                  // 128 KB
  const int tid = threadIdx.x;
  const int blk = blockIdx.x;
  const bool isL1 = (blk < 128);
  const int  lblk = isL1 ? blk : (blk - 128);
  const int  shard = lblk & 7;

  // ---- pack this block's weight slice fp32 -> bf16 LDS (all 8 waves) ----
  {
    const int nsec = isL1 ? 6144 : 8192;
    for (int i = tid; i < nsec; i += 512){
      int m = i & 15, grp_ = (i >> 4) & 3, T = (i >> 6) & 1, s = i >> 7;
      const float* W; int K, ks;
      if (isL1){
        if (s < 16){ W = Wih1; K = 512;  ks = s;      }
        else       { W = Whh1; K = 1024; ks = s - 16; }
      } else {
        if (s < 32){ W = Wih2; K = 1024; ks = s;      }
        else       { W = Whh2; K = 1024; ks = s - 32; }
      }
      int u = m >> 2, r = m & 3;
      const float* src = W + (size_t)(r*HID + lblk*8 + T*4 + u)*K + ks*32 + grp_*8;
      float4 a = *(const float4*)src;
      float4 c = *(const float4*)(src + 4);
      u32x4 o;
      o.x = pack2(a.x, a.y); o.y = pack2(a.z, a.w);
      o.z = pack2(c.x, c.y); o.w = pack2(c.z, c.w);
      sW[i] = o;
    }
  }

  const int w   = tid >> 6, l = tid & 63;
  const int grp = l >> 4,  col = l & 15;
  const u32x4* h04 = (const u32x4*)h0P;
  const u32x4* h14 = (const u32x4*)h1P;
  __syncthreads();                            // weights visible; last barrier

  if (w < 4){
    // ================== RECURRENCE WAVES (round-8 logic, unchanged) =======
    const int b    = w*16 + col;
    const int aoff = l;
    const int boff = grp*64 + b;
    const int unitA = lblk*8 + grp;
    const int unitB = lblk*8 + 4 + grp;
    float bsA[4], bsB[4];
    #pragma unroll
    for (int r = 0; r < 4; ++r){
      if (isL1){
        bsA[r] = bi1[r*HID + unitA] + bh1[r*HID + unitA];
        bsB[r] = bi1[r*HID + unitB] + bh1[r*HID + unitB];
      } else {
        bsA[r] = bi2[r*HID + unitA] + bh2[r*HID + unitA];
        bsB[r] = bi2[r*HID + unitB] + bh2[r*HID + unitB];
      }
    }
    float cA = 0.f, cB = 0.f;

    if (isL1){
      for (int t = 0; t < TX; ++t){
        f32x4 a00={0,0,0,0}, a01={0,0,0,0}, a10={0,0,0,0}, a11={0,0,0,0};
        {
          const u32x4* Bx = xP + (size_t)t*4096;
          #pragma unroll
          for (int s = 0; s < 16; s += 2){
            u32x4 B0 = Bx[s*256 + boff], B1 = Bx[(s+1)*256 + boff];
            MFMA(a00, sW[(s*2+0)*64 + aoff], B0);
            MFMA(a10, sW[(s*2+1)*64 + aoff], B0);
            MFMA(a01, sW[(s*2+2)*64 + aoff], B1);
            MFMA(a11, sW[(s*2+3)*64 + aoff], B1);
          }
        }
        if (t > 0) pollw(cnt0a + ((size_t)(t-1)*4 + w)*256);
        {
          const u32x4* Bh = h04 + (size_t)t*SLAB_V4;
          #pragma unroll
          for (int s = 0; s < 32; s += 2){
            u32x4 B0 = Bh[s*256 + boff], B1 = Bh[(s+1)*256 + boff];
            MFMA(a00, sW[((16+s)*2+0)*64 + aoff], B0);
            MFMA(a10, sW[((16+s)*2+1)*64 + aoff], B0);
            MFMA(a01, sW[((17+s)*2+0)*64 + aoff], B1);
            MFMA(a11, sW[((17+s)*2+1)*64 + aoff], B1);
          }
        }
        u32 m0 = cell_h(a00, a01, bsA, cA);
        u32 m1 = cell_h(a10, a11, bsB, cB);
        pub_store(h0P + (size_t)(t+1)*SLAB_U16 + (lblk<<9) + (w<<7), m0, m1);
        pub_signal(cnt0b + (((size_t)t*4 + w)*8 + shard)*32,
                   cnt0a + (((size_t)t*4 + w)*8 + shard)*32);
      }
    } else {
      pollw(cnt0b + (size_t)(0*4 + w)*256);
      for (int t = 0; t < TX; ++t){
        f32x4 a00={0,0,0,0}, a01={0,0,0,0}, a10={0,0,0,0}, a11={0,0,0,0};
        {
          const u32x4* Bh = h04 + (size_t)(t+1)*SLAB_V4;
          #pragma unroll
          for (int s = 0; s < 32; s += 2){
            u32x4 B0 = Bh[s*256 + boff], B1 = Bh[(s+1)*256 + boff];
            MFMA(a00, sW[(s*2+0)*64 + aoff], B0);
            MFMA(a10, sW[(s*2+1)*64 + aoff], B0);
            MFMA(a01, sW[((s+1)*2+0)*64 + aoff], B1);
            MFMA(a11, sW[((s+1)*2+1)*64 + aoff], B1);
          }
        }
        if (t > 0) pollw(cnt1 + ((size_t)(t-1)*4 + w)*256);
        {
          const u32x4* Bh = h14 + (size_t)t*SLAB_V4;
          #pragma unroll
          for (int s = 0; s < 32; s += 2){
            u32x4 B0 = Bh[s*256 + boff], B1 = Bh[(s+1)*256 + boff];
            MFMA(a00, sW[((32+s)*2+0)*64 + aoff], B0);
            MFMA(a10, sW[((32+s)*2+1)*64 + aoff], B0);
            MFMA(a01, sW[((33+s)*2+0)*64 + aoff], B1);
            MFMA(a11, sW[((33+s)*2+1)*64 + aoff], B1);
          }
        }
        u32 m0 = cell_h(a00, a01, bsA, cA);
        u32 m1 = cell_h(a10, a11, bsB, cB);
        pub_store(h1P + (size_t)(t+1)*SLAB_U16 + (lblk<<9) + (w<<7), m0, m1);
        if (t + 1 < TX) pollw(cnt0b + ((size_t)(t+1)*4 + w)*256);
        pub_signal(cnt1 + (((size_t)t*4 + w)*8 + shard)*32, (int*)0);
      }
    }
  } else {
    // ================== OUT-PROJECTION WAVES ===============================
    const int g     = blk*4 + (w - 4);        // 0..1023
    const int vt    = g & 127;
    const int phase = g >> 7;                 // 0..7
    const u32x4* WP = WoutP + (size_t)vt*4096;
    const float bias = b_out[vt*16 + col];

    for (int i = 0; i < TX/8; ++i){
      const int t = phase + i*8;
      pollt(cnt1, t);
      const u32x4* Bh = h14 + (size_t)(t+1)*SLAB_V4;
      f32x4 acc[4];
      #pragma unroll
      for (int bg = 0; bg < 4; ++bg) acc[bg] = (f32x4){0,0,0,0};

      for (int s = 0; s < 32; ++s){
        u32x4 Whi = WP[(s*2+0)*64 + l];
        u32x4 Wlo = WP[(s*2+1)*64 + l];
        const u32x4* Ab = Bh + (s*4 + grp)*64;
        #pragma unroll
        for (int bg = 0; bg < 4; ++bg){
          u32x4 A = Ab[bg*16 + col];
          MFMA(acc[bg], A, Whi);
          MFMA(acc[bg], A, Wlo);
        }
      }
      // D: col(lane&15)=v, row=(lane>>4)*4+r=b-within-16 -> coalesced 64B
      #pragma unroll
      for (int bg = 0; bg < 4; ++bg){
        #pragma unroll
        for (int r = 0; r < 4; ++r){
          int bb = bg*16 + grp*4 + r;
          out[((size_t)t*BATCH + bb)*VOCAB + vt*16 + col] = acc[bg][r] + bias;
        }
      }
    }
  }
}

// ---------------------------------------------------------------------------
extern "C" void kernel_launch(void* const* d_in, const int* in_sizes, int n_in,
                              void* d_out, int out_size, void* d_ws, size_t ws_size,
                              hipStream_t stream)
{
  const int*   x     = (const int*)  d_in[0];
  const float* emb   = (const float*)d_in[1];
  const float* W_ih1 = (const float*)d_in[2];
  const float* W_hh1 = (const float*)d_in[3];
  const float* b_ih1 = (const float*)d_in[4];
  const float* b_hh1 = (const float*)d_in[5];
  const float* W_ih2 = (const float*)d_in[6];
  const float* W_hh2 = (const float*)d_in[7];
  const float* b_ih2 = (const float*)d_in[8];
  const float* b_hh2 = (const float*)d_in[9];
  const float* W_out = (const float*)d_in[10];
  const float* b_out = (const float*)d_in[11];
  float* out = (float*)d_out;

  char* ws = (char*)d_ws;
  int*   cnt0a = (int*)  (ws + OFF_CNT0A);
  int*   cnt0b = (int*)  (ws + OFF_CNT0B);
  int*   cnt1  = (int*)  (ws + OFF_CNT1);
  u16*   h0P   = (u16*)  (ws + OFF_H0);
  u16*   h1P   = (u16*)  (ws + OFF_H1);
  u32x4* xP    = (u32x4*)(ws + OFF_XP);
  u32x4* WoutP = (u32x4*)(ws + OFF_WOUT);

  hipMemsetAsync(ws, 0, 3145728, stream);              // all counters
  hipMemsetAsync(ws + OFF_H0, 0, 131072, stream);      // h0 slab 0 = zeros
  hipMemsetAsync(ws + OFF_H1, 0, 131072, stream);      // h1 slab 0 = zeros

  prologue_pack<<<6144, 256, 0, stream>>>(x, emb, W_out, xP, WoutP);

  lstm_persist<<<256, 512, 0, stream>>>(
      xP, h0P, h1P, WoutP, b_out, out,
      W_ih1, W_hh1, W_ih2, W_hh2,
      b_ih1, b_hh1, b_ih2, b_hh2, cnt0a, cnt0b, cnt1);
}

// Round 10
// 2603.048 us; speedup vs baseline: 1.3872x; 1.3872x over previous
//
#include <hip/hip_runtime.h>
#include <math.h>
#include <stdint.h>

#define VOCAB 2048
#define EMB   512
#define HID   1024
#define TX    256
#define BATCH 64

typedef __attribute__((ext_vector_type(8))) short bf16x8;
typedef __attribute__((ext_vector_type(4))) float f32x4;
typedef unsigned int u32;
typedef unsigned short u16;
typedef unsigned long long u64;
typedef __attribute__((ext_vector_type(4))) u32 u32x4;

// ---------------- ws byte offsets ----------------
// cnt0a/cnt0b/cnt1 : [256 t][4 wave][8 shard] counters, 128B-strided words.
// xrdy  : [256 t] flags, 128B-strided (block t packed xP slice t)
// h0P   : 257 slabs of [128 kblk][64 b][8] bf16
// h1P   : 257 slabs (slab 0 zeroed)
// xP    : [TX][64 kblk][64 b][8] bf16
#define OFF_CNT0A 0u
#define OFF_CNT0B 1048576u
#define OFF_CNT1  2097152u
#define OFF_XRDY  3145728u
#define OFF_H0    3178496u
#define OFF_H1    36864000u
#define OFF_XP    70549504u
#define SLAB_U16  65536u
#define SLAB_V4   8192u

__device__ __forceinline__ u16 f2bf(float x){
  u32 v = __float_as_uint(x);
  v += 0x7fffu + ((v >> 16) & 1u);          // RNE
  return (u16)(v >> 16);
}
__device__ __forceinline__ u32 pack2(float a, float b){
  return (u32)f2bf(a) | ((u32)f2bf(b) << 16);
}
__device__ __forceinline__ float bf2f(u16 h){ return __uint_as_float(((u32)h) << 16); }
__device__ __forceinline__ float sigm(float x){ return 1.f/(1.f+__expf(-x)); }
__device__ __forceinline__ float tanh_(float x){
  float e = __expf(2.f*fabsf(x));           // overflow-safe
  return copysignf(1.f - 2.f/(e+1.f), x);
}

// ---------------------------------------------------------------------------
// Persistent LSTM (round-8 structure + poll-prefetch + fused embed pack).
// 256 blocks x 256 threads, 1 block/CU. Blocks 0..127 = L1, 128..255 = L2.
// Phase A: block t packs xP slice t (agent stores) and raises xrdy[t].
// Chains: wave-decoupled counters, zero block barriers in the t-loop.
// All polls are register-prefetched: load issued early, checked after the
// covering GEMM / publish drain; spin only on miss.
// ---------------------------------------------------------------------------
#define MFMA(ACC, AV, BV)                                                       \
  ACC = __builtin_amdgcn_mfma_f32_16x16x32_bf16(                                \
      *(bf16x8*)&(AV), *(bf16x8*)&(BV), ACC, 0, 0, 0)

__device__ __forceinline__ u32 cell_h(const f32x4& A, const f32x4& B,
                                      const float* bs, float& c){
  float p0=A[0]+B[0]+bs[0], p1=A[1]+B[1]+bs[1];
  float p2=A[2]+B[2]+bs[2], p3=A[3]+B[3]+bs[3];
  float iv=sigm(p0), fv=sigm(p1), gv=tanh_(p2), ov=sigm(p3);
  c = fv*c + iv*gv;
  return (u32)f2bf(ov*tanh_(c));
}

// one-shot 8-shard counter read (lanes 0..7), for prefetch-check pattern
__device__ __forceinline__ int try8(const int* base){
  const int l = threadIdx.x & 63;
  return (l < 8) ? __hip_atomic_load(base + (l & 7)*32, __ATOMIC_RELAXED,
                                     __HIP_MEMORY_SCOPE_AGENT)
                 : 16;
}
__device__ __forceinline__ void pollw(const int* base){
  const int l = threadIdx.x & 63;
  const int* c = base + (l & 7)*32;
  const bool mine = (l < 8);
  for (;;){
    int v = mine ? __hip_atomic_load(c, __ATOMIC_RELAXED, __HIP_MEMORY_SCOPE_AGENT)
                 : 16;
    if (__all(v >= 16)) break;
    __builtin_amdgcn_s_sleep(1);
  }
}
__device__ __forceinline__ int try1(const int* p){
  return ((threadIdx.x & 63) == 0)
       ? __hip_atomic_load(p, __ATOMIC_RELAXED, __HIP_MEMORY_SCOPE_AGENT) : 1;
}
__device__ __forceinline__ void poll1(const int* p){
  const bool mine = ((threadIdx.x & 63) == 0);
  for (;;){
    int v = mine ? __hip_atomic_load(p, __ATOMIC_RELAXED, __HIP_MEMORY_SCOPE_AGENT)
                 : 1;
    if (__all(v >= 1)) break;
    __builtin_amdgcn_s_sleep(1);
  }
}

__device__ __forceinline__ void pub_store(u16* dstp, u32 m0, u32 m1){
  const int l = threadIdx.x & 63;
  u32 p = m0 | (m1 << 16);
  int col = l & 15;
  u32 q0 = (u32)__shfl((int)p, col);
  u32 q1 = (u32)__shfl((int)p, col + 16);
  u32 q2 = (u32)__shfl((int)p, col + 32);
  u32 q3 = (u32)__shfl((int)p, col + 48);
  if (l < 16){
    u64 lo = ((u64)((q2 & 0xffffu) | (q3 << 16)) << 32)
           |  (u64)((q0 & 0xffffu) | (q1 << 16));
    u64 hi = ((u64)((q2 >> 16) | (q3 & 0xffff0000u)) << 32)
           |  (u64)((q0 >> 16) | (q1 & 0xffff0000u));
    u64* dst = (u64*)(dstp + (size_t)l*8);
    __hip_atomic_store(dst,     lo, __ATOMIC_RELAXED, __HIP_MEMORY_SCOPE_AGENT);
    __hip_atomic_store(dst + 1, hi, __ATOMIC_RELAXED, __HIP_MEMORY_SCOPE_AGENT);
  }
}

__device__ __forceinline__ void pub_signal(int* add1, int* add2){
  asm volatile("s_waitcnt vmcnt(0)" ::: "memory");   // wave-local drain
  if ((threadIdx.x & 63) == 0){
    __hip_atomic_fetch_add(add1, 1, __ATOMIC_RELAXED, __HIP_MEMORY_SCOPE_AGENT);
    if (add2)
      __hip_atomic_fetch_add(add2, 1, __ATOMIC_RELAXED, __HIP_MEMORY_SCOPE_AGENT);
  }
}

__global__ __launch_bounds__(256, 1) void lstm_persist(
    const int* __restrict__ x, const float* __restrict__ emb,
    u32x4* __restrict__ xP, u16* __restrict__ h0P, u16* __restrict__ h1P,
    const float* __restrict__ Wih1, const float* __restrict__ Whh1,
    const float* __restrict__ Wih2, const float* __restrict__ Whh2,
    const float* __restrict__ bi1, const float* __restrict__ bh1,
    const float* __restrict__ bi2, const float* __restrict__ bh2,
    int* __restrict__ cnt0a, int* __restrict__ cnt0b, int* __restrict__ cnt1,
    int* __restrict__ xrdy)
{
  __shared__ u32x4 sW[8192];                  // 128 KB
  const int tid = threadIdx.x;
  const int blk = blockIdx.x;
  const bool isL1 = (blk < 128);
  const int  lblk = isL1 ? blk : (blk - 128);
  const int  shard = lblk & 7;

  // ---- Phase A: pack xP slice t = blk (agent-scope stores) ----
  {
    const int t = blk;
    for (int n = tid; n < 4096; n += 256){
      int b = n & 63, kblk = n >> 6;
      int idx = x[b*TX + t];
      const float* src = emb + (size_t)idx*EMB + kblk*8;
      u32x4 o;
      o.x = pack2(src[0], src[1]);
      o.y = pack2(src[2], src[3]);
      o.z = pack2(src[4], src[5]);
      o.w = pack2(src[6], src[7]);
      u64* dst = (u64*)&xP[(size_t)t*4096 + n];
      __hip_atomic_store(dst,     ((u64)(u32)o.y << 32) | (u32)o.x,
                         __ATOMIC_RELAXED, __HIP_MEMORY_SCOPE_AGENT);
      __hip_atomic_store(dst + 1, ((u64)(u32)o.w << 32) | (u32)o.z,
                         __ATOMIC_RELAXED, __HIP_MEMORY_SCOPE_AGENT);
    }
  }
  __syncthreads();                            // all waves' stores drained
  if (tid == 0)
    __hip_atomic_store(xrdy + blk*32, 1, __ATOMIC_RELAXED,
                       __HIP_MEMORY_SCOPE_AGENT);

  // ---- Phase B: pack this block's weight slice fp32 -> bf16 LDS ----
  {
    const int nsec = isL1 ? 6144 : 8192;
    for (int i = tid; i < nsec; i += 256){
      int m = i & 15, grp_ = (i >> 4) & 3, T = (i >> 6) & 1, s = i >> 7;
      const float* W; int K, ks;
      if (isL1){
        if (s < 16){ W = Wih1; K = 512;  ks = s;      }
        else       { W = Whh1; K = 1024; ks = s - 16; }
      } else {
        if (s < 32){ W = Wih2; K = 1024; ks = s;      }
        else       { W = Whh2; K = 1024; ks = s - 32; }
      }
      int u = m >> 2, r = m & 3;
      const float* src = W + (size_t)(r*HID + lblk*8 + T*4 + u)*K + ks*32 + grp_*8;
      float4 a = *(const float4*)src;
      float4 c = *(const float4*)(src + 4);
      u32x4 o;
      o.x = pack2(a.x, a.y); o.y = pack2(a.z, a.w);
      o.z = pack2(c.x, c.y); o.w = pack2(c.z, c.w);
      sW[i] = o;
    }
  }

  const int w    = tid >> 6, l = tid & 63;
  const int grp  = l >> 4,  col = l & 15;
  const int b    = w*16 + col;
  const int aoff = l;
  const int boff = grp*64 + b;

  const int unitA = lblk*8 + grp;
  const int unitB = lblk*8 + 4 + grp;
  float bsA[4], bsB[4];
  #pragma unroll
  for (int r = 0; r < 4; ++r){
    if (isL1){
      bsA[r] = bi1[r*HID + unitA] + bh1[r*HID + unitA];
      bsB[r] = bi1[r*HID + unitB] + bh1[r*HID + unitB];
    } else {
      bsA[r] = bi2[r*HID + unitA] + bh2[r*HID + unitA];
      bsB[r] = bi2[r*HID + unitB] + bh2[r*HID + unitB];
    }
  }
  float cA = 0.f, cB = 0.f;
  const u32x4* h04 = (const u32x4*)h0P;
  const u32x4* h14 = (const u32x4*)h1P;
  __syncthreads();                            // weights visible; last barrier

  if (isL1){
    // ================= LAYER-1 blocks =================
    int xv = try1(xrdy + 0*32);               // prefetch xrdy[0]
    for (int t = 0; t < TX; ++t){
      if (!__all(xv >= 1)) poll1(xrdy + t*32);
      asm volatile("" ::: "memory");
      int pv = 16;
      if (t > 0) pv = try8(cnt0a + ((size_t)(t-1)*4 + w)*256);  // issue early
      asm volatile("" ::: "memory");
      f32x4 a00={0,0,0,0}, a01={0,0,0,0}, a10={0,0,0,0}, a11={0,0,0,0};
      {
        const u32x4* Bx = xP + (size_t)t*4096;
        #pragma unroll
        for (int s = 0; s < 16; s += 2){
          u32x4 B0 = Bx[s*256 + boff], B1 = Bx[(s+1)*256 + boff];
          MFMA(a00, sW[(s*2+0)*64 + aoff], B0);
          MFMA(a10, sW[(s*2+1)*64 + aoff], B0);
          MFMA(a01, sW[(s*2+2)*64 + aoff], B1);
          MFMA(a11, sW[(s*2+3)*64 + aoff], B1);
        }
      }
      if (!__all(pv >= 16)) pollw(cnt0a + ((size_t)(t-1)*4 + w)*256);
      asm volatile("" ::: "memory");
      {
        const u32x4* Bh = h04 + (size_t)t*SLAB_V4;
        #pragma unroll
        for (int s = 0; s < 32; s += 2){
          u32x4 B0 = Bh[s*256 + boff], B1 = Bh[(s+1)*256 + boff];
          MFMA(a00, sW[((16+s)*2+0)*64 + aoff], B0);
          MFMA(a10, sW[((16+s)*2+1)*64 + aoff], B0);
          MFMA(a01, sW[((17+s)*2+0)*64 + aoff], B1);
          MFMA(a11, sW[((17+s)*2+1)*64 + aoff], B1);
        }
      }
      u32 m0 = cell_h(a00, a01, bsA, cA);
      u32 m1 = cell_h(a10, a11, bsB, cB);
      pub_store(h0P + (size_t)(t+1)*SLAB_U16 + (lblk<<9) + (w<<7), m0, m1);
      xv = (t + 1 < TX) ? try1(xrdy + (t+1)*32) : 1;   // covered by drain
      pub_signal(cnt0b + (((size_t)t*4 + w)*8 + shard)*32,
                 cnt0a + (((size_t)t*4 + w)*8 + shard)*32);
    }
  } else {
    // ================= LAYER-2 blocks =================
    pollw(cnt0b + (size_t)(0*4 + w)*256);     // prologue: h0(1) ready
    asm volatile("" ::: "memory");
    for (int t = 0; t < TX; ++t){
      int pv1 = 16;
      if (t > 0) pv1 = try8(cnt1 + ((size_t)(t-1)*4 + w)*256); // issue early
      asm volatile("" ::: "memory");
      f32x4 a00={0,0,0,0}, a01={0,0,0,0}, a10={0,0,0,0}, a11={0,0,0,0};
      {
        const u32x4* Bh = h04 + (size_t)(t+1)*SLAB_V4;
        #pragma unroll
        for (int s = 0; s < 32; s += 2){
          u32x4 B0 = Bh[s*256 + boff], B1 = Bh[(s+1)*256 + boff];
          MFMA(a00, sW[(s*2+0)*64 + aoff], B0);
          MFMA(a10, sW[(s*2+1)*64 + aoff], B0);
          MFMA(a01, sW[((s+1)*2+0)*64 + aoff], B1);
          MFMA(a11, sW[((s+1)*2+1)*64 + aoff], B1);
        }
      }
      if (!__all(pv1 >= 16)) pollw(cnt1 + ((size_t)(t-1)*4 + w)*256);
      asm volatile("" ::: "memory");
      {
        const u32x4* Bh = h14 + (size_t)t*SLAB_V4;
        #pragma unroll
        for (int s = 0; s < 32; s += 2){
          u32x4 B0 = Bh[s*256 + boff], B1 = Bh[(s+1)*256 + boff];
          MFMA(a00, sW[((32+s)*2+0)*64 + aoff], B0);
          MFMA(a10, sW[((32+s)*2+1)*64 + aoff], B0);
          MFMA(a01, sW[((33+s)*2+0)*64 + aoff], B1);
          MFMA(a11, sW[((33+s)*2+1)*64 + aoff], B1);
        }
      }
      u32 m0 = cell_h(a00, a01, bsA, cA);
      u32 m1 = cell_h(a10, a11, bsB, cB);
      pub_store(h1P + (size_t)(t+1)*SLAB_U16 + (lblk<<9) + (w<<7), m0, m1);
      int pv0 = (t + 1 < TX) ? try8(cnt0b + ((size_t)(t+1)*4 + w)*256) : 16;
      pub_signal(cnt1 + (((size_t)t*4 + w)*8 + shard)*32, (int*)0);
      if (!__all(pv0 >= 16)) pollw(cnt0b + ((size_t)(t+1)*4 + w)*256);
      asm volatile("" ::: "memory");
    }
  }
}

// ---------------------------------------------------------------------------
// MFMA output projection with split-precision W_out (bf16 hi + bf16 lo).
// (unchanged from round 8)
// ---------------------------------------------------------------------------
__global__ __launch_bounds__(256, 1) void out_gemm(
    const u16* __restrict__ h1P, const float* __restrict__ W_out,
    const float* __restrict__ b_out, float* __restrict__ out)
{
  __shared__ u32x4 sA[8192];                  // 128 KB (A hi/lo chunk; C reuse)
  const int tid = threadIdx.x, l = tid & 63, w = tid >> 6;
  const int grp = l >> 4, col = l & 15;
  const int b   = w*16 + col;
  const int vbase = blockIdx.x * 128;
  const int t0    = blockIdx.y * 4;

  f32x4 acc0[8], acc1[8], acc2[8], acc3[8];
  #pragma unroll
  for (int m = 0; m < 8; ++m){
    acc0[m]=(f32x4){0,0,0,0}; acc1[m]=(f32x4){0,0,0,0};
    acc2[m]=(f32x4){0,0,0,0}; acc3[m]=(f32x4){0,0,0,0};
  }
  const u32x4* h14 = (const u32x4*)h1P;

  for (int kc = 0; kc < 4; ++kc){
    __syncthreads();
    #pragma unroll
    for (int k = 0; k < 16; ++k){
      int j = tid + k*256;
      int lane = j & 63, mt = (j >> 6) & 7, s = j >> 9;
      int v  = vbase + mt*16 + (lane & 15);
      int kk = kc*256 + s*32 + (lane >> 4)*8;
      const float* src = W_out + (size_t)v*HID + kk;
      float4 f0 = *(const float4*)src, f1 = *(const float4*)(src + 4);
      float e[8] = {f0.x,f0.y,f0.z,f0.w,f1.x,f1.y,f1.z,f1.w};
      u16 hi[8]; float lo[8];
      #pragma unroll
      for (int r = 0; r < 8; ++r){ hi[r] = f2bf(e[r]); lo[r] = e[r] - bf2f(hi[r]); }
      u32x4 H, L;
      H.x = (u32)hi[0]|((u32)hi[1]<<16); H.y = (u32)hi[2]|((u32)hi[3]<<16);
      H.z = (u32)hi[4]|((u32)hi[5]<<16); H.w = (u32)hi[6]|((u32)hi[7]<<16);
      L.x = pack2(lo[0],lo[1]); L.y = pack2(lo[2],lo[3]);
      L.z = pack2(lo[4],lo[5]); L.w = pack2(lo[6],lo[7]);
      int base = (s*8 + mt)*128 + lane;
      sA[base]      = H;
      sA[base + 64] = L;
    }
    __syncthreads();

    #pragma unroll
    for (int s = 0; s < 8; ++s){
      int ksl = kc*8 + s;
      int bi  = ksl*256 + grp*64 + b;
      u32x4 B0 = h14[(size_t)(t0+1)*SLAB_V4 + bi];
      u32x4 B1 = h14[(size_t)(t0+2)*SLAB_V4 + bi];
      u32x4 B2 = h14[(size_t)(t0+3)*SLAB_V4 + bi];
      u32x4 B3 = h14[(size_t)(t0+4)*SLAB_V4 + bi];
      #pragma unroll
      for (int mt = 0; mt < 8; ++mt){
        u32x4 Ah = sA[(s*8 + mt)*128 + l];
        u32x4 Al = sA[(s*8 + mt)*128 + 64 + l];
        MFMA(acc0[mt], Ah, B0); MFMA(acc1[mt], Ah, B1);
        MFMA(acc2[mt], Ah, B2); MFMA(acc3[mt], Ah, B3);
        MFMA(acc0[mt], Al, B0); MFMA(acc1[mt], Al, B1);
        MFMA(acc2[mt], Al, B2); MFMA(acc3[mt], Al, B3);
      }
    }
  }

  float* sC = (float*)sA;                     // [64][132] fp32
#define EPILOGUE(ACC, TT)                                                       \
  {                                                                             \
    __syncthreads();                                                            \
    _Pragma("unroll")                                                           \
    for (int mt = 0; mt < 8; ++mt){                                             \
      f32x4 a = ACC[mt];                                                        \
      _Pragma("unroll")                                                         \
      for (int r = 0; r < 4; ++r)                                               \
        sC[b*132 + mt*16 + grp*4 + r] = a[r];                                   \
    }                                                                           \
    __syncthreads();                                                            \
    {                                                                           \
      int bb = tid >> 2, q = tid & 3;                                           \
      const float* cp = sC + bb*132 + q*32;                                     \
      const float* bo = b_out + vbase + q*32;                                   \
      float* op = out + ((size_t)(t0+TT)*BATCH + bb)*VOCAB + vbase + q*32;      \
      _Pragma("unroll")                                                         \
      for (int j = 0; j < 8; ++j){                                              \
        float4 cv = *(const float4*)(cp + j*4);                                 \
        float4 bv = *(const float4*)(bo + j*4);                                 \
        float4 ov = {cv.x+bv.x, cv.y+bv.y, cv.z+bv.z, cv.w+bv.w};               \
        *(float4*)(op + j*4) = ov;                                              \
      }                                                                         \
    }                                                                           \
  }
  EPILOGUE(acc0, 0)
  EPILOGUE(acc1, 1)
  EPILOGUE(acc2, 2)
  EPILOGUE(acc3, 3)
#undef EPILOGUE
}

// ---------------------------------------------------------------------------
extern "C" void kernel_launch(void* const* d_in, const int* in_sizes, int n_in,
                              void* d_out, int out_size, void* d_ws, size_t ws_size,
                              hipStream_t stream)
{
  const int*   x     = (const int*)  d_in[0];
  const float* emb   = (const float*)d_in[1];
  const float* W_ih1 = (const float*)d_in[2];
  const float* W_hh1 = (const float*)d_in[3];
  const float* b_ih1 = (const float*)d_in[4];
  const float* b_hh1 = (const float*)d_in[5];
  const float* W_ih2 = (const float*)d_in[6];
  const float* W_hh2 = (const float*)d_in[7];
  const float* b_ih2 = (const float*)d_in[8];
  const float* b_hh2 = (const float*)d_in[9];
  const float* W_out = (const float*)d_in[10];
  const float* b_out = (const float*)d_in[11];
  float* out = (float*)d_out;

  char* ws = (char*)d_ws;
  int*   cnt0a = (int*)  (ws + OFF_CNT0A);
  int*   cnt0b = (int*)  (ws + OFF_CNT0B);
  int*   cnt1  = (int*)  (ws + OFF_CNT1);
  int*   xrdy  = (int*)  (ws + OFF_XRDY);
  u16*   h0P   = (u16*)  (ws + OFF_H0);
  u16*   h1P   = (u16*)  (ws + OFF_H1);
  u32x4* xP    = (u32x4*)(ws + OFF_XP);

  hipMemsetAsync(ws, 0, 3178496, stream);              // counters + xrdy
  hipMemsetAsync(ws + OFF_H0, 0, 131072, stream);      // h0 slab 0 = zeros
  hipMemsetAsync(ws + OFF_H1, 0, 131072, stream);      // h1 slab 0 = zeros

  lstm_persist<<<256, 256, 0, stream>>>(
      x, emb, xP, h0P, h1P,
      W_ih1, W_hh1, W_ih2, W_hh2,
      b_ih1, b_hh1, b_ih2, b_hh2, cnt0a, cnt0b, cnt1, xrdy);

  dim3 og(VOCAB/128, TX/4);
  out_gemm<<<og, 256, 0, stream>>>(h1P, W_out, b_out, out);
}

// Round 11
// 1423.573 us; speedup vs baseline: 2.5366x; 1.8285x over previous
//
#include <hip/hip_runtime.h>
#include <math.h>
#include <stdint.h>

#define VOCAB 2048
#define EMB   512
#define HID   1024
#define TX    256
#define BATCH 64

typedef __attribute__((ext_vector_type(8))) short bf16x8;
typedef __attribute__((ext_vector_type(4))) float f32x4;
typedef unsigned int u32;
typedef unsigned short u16;
typedef unsigned long long u64;
typedef __attribute__((ext_vector_type(4))) u32 u32x4;

// ---------------- ws byte offsets ----------------
// cnt0a/cnt0b/cnt1 : [256 t][4 wave][8 shard] counters, 128B-strided words.
//   producer wave w of block lblk bumps (t, w, lblk&7); target count 16.
// h0P : 257 slabs of [128 kblk][64 b][8] bf16  (slab t+1 = h0 after step t)
// h1P : 257 slabs (slab 0 zeroed)
// xP  : [TX][64 kblk][64 b][8] bf16
#define OFF_CNT0A 0u
#define OFF_CNT0B 1048576u
#define OFF_CNT1  2097152u
#define OFF_H0    3145728u
#define OFF_H1    36831232u
#define OFF_XP    70516736u
#define SLAB_U16  65536u
#define SLAB_V4   8192u

__device__ __forceinline__ u16 f2bf(float x){
  u32 v = __float_as_uint(x);
  v += 0x7fffu + ((v >> 16) & 1u);          // RNE
  return (u16)(v >> 16);
}
__device__ __forceinline__ u32 pack2(float a, float b){
  return (u32)f2bf(a) | ((u32)f2bf(b) << 16);
}
__device__ __forceinline__ float bf2f(u16 h){ return __uint_as_float(((u32)h) << 16); }
__device__ __forceinline__ float sigm(float x){ return 1.f/(1.f+__expf(-x)); }
__device__ __forceinline__ float tanh_(float x){
  float e = __expf(2.f*fabsf(x));           // overflow-safe
  return copysignf(1.f - 2.f/(e+1.f), x);
}

// ---------------------------------------------------------------------------
__global__ __launch_bounds__(256) void embed_pack(
    const int* __restrict__ x, const float* __restrict__ emb, u32x4* __restrict__ xP)
{
  int flat = blockIdx.x*256 + threadIdx.x;   // t*4096 + kblk*64 + b
  int b    = flat & 63;
  int kblk = (flat >> 6) & 63;
  int t    = flat >> 12;
  int idx  = x[b*TX + t];
  const float* src = emb + (size_t)idx*EMB + kblk*8;
  u32x4 o;
  o.x = pack2(src[0], src[1]);
  o.y = pack2(src[2], src[3]);
  o.z = pack2(src[4], src[5]);
  o.w = pack2(src[6], src[7]);
  xP[flat] = o;
}

// ---------------------------------------------------------------------------
// Layer-specialized persistent LSTM, wave-decoupled (round-8 optimum).
// Blocks 0..127 = L1, 128..255 = L2; block owns 8 units, weights bf16 in LDS.
// Each wave w handles batches 16w..16w+15 end-to-end; producer wave w's
// output is consumed ONLY by consumer waves w, so sync is per-(t,wave,shard)
// counters and the t-loop has ZERO block barriers.
// ---------------------------------------------------------------------------
#define MFMA(ACC, AV, BV)                                                       \
  ACC = __builtin_amdgcn_mfma_f32_16x16x32_bf16(                                \
      *(bf16x8*)&(AV), *(bf16x8*)&(BV), ACC, 0, 0, 0)

__device__ __forceinline__ u32 cell_h(const f32x4& A, const f32x4& B,
                                      const float* bs, float& c){
  float p0=A[0]+B[0]+bs[0], p1=A[1]+B[1]+bs[1];
  float p2=A[2]+B[2]+bs[2], p3=A[3]+B[3]+bs[3];
  float iv=sigm(p0), fv=sigm(p1), gv=tanh_(p2), ov=sigm(p3);
  c = fv*c + iv*gv;
  return (u32)f2bf(ov*tanh_(c));
}

// wave-level poll: lanes 0..7 watch the 8 shard words, all lanes spin on __all
__device__ __forceinline__ void pollw(const int* base){
  const int l = threadIdx.x & 63;
  const int* c = base + (l & 7)*32;          // 128B-strided shard words
  const bool mine = (l < 8);
  for (;;){
    int v = mine ? __hip_atomic_load(c, __ATOMIC_RELAXED, __HIP_MEMORY_SCOPE_AGENT)
                 : 16;
    if (__all(v >= 16)) break;
    __builtin_amdgcn_s_sleep(1);
  }
  asm volatile("" ::: "memory");             // no hoisting of slab loads above
}

// in-wave transpose + 16B stores (lanes 0..15); no LDS, no barrier
__device__ __forceinline__ void pub_store(u16* dstp, u32 m0, u32 m1){
  const int l = threadIdx.x & 63;
  u32 p = m0 | (m1 << 16);
  int col = l & 15;
  u32 q0 = (u32)__shfl((int)p, col);
  u32 q1 = (u32)__shfl((int)p, col + 16);
  u32 q2 = (u32)__shfl((int)p, col + 32);
  u32 q3 = (u32)__shfl((int)p, col + 48);
  if (l < 16){
    u64 lo = ((u64)((q2 & 0xffffu) | (q3 << 16)) << 32)
           |  (u64)((q0 & 0xffffu) | (q1 << 16));
    u64 hi = ((u64)((q2 >> 16) | (q3 & 0xffff0000u)) << 32)
           |  (u64)((q0 >> 16) | (q1 & 0xffff0000u));
    u64* dst = (u64*)(dstp + (size_t)l*8);
    __hip_atomic_store(dst,     lo, __ATOMIC_RELAXED, __HIP_MEMORY_SCOPE_AGENT);
    __hip_atomic_store(dst + 1, hi, __ATOMIC_RELAXED, __HIP_MEMORY_SCOPE_AGENT);
  }
}

__device__ __forceinline__ void pub_signal(int* add1, int* add2){
  asm volatile("s_waitcnt vmcnt(0)" ::: "memory");   // wave-local drain
  if ((threadIdx.x & 63) == 0){
    __hip_atomic_fetch_add(add1, 1, __ATOMIC_RELAXED, __HIP_MEMORY_SCOPE_AGENT);
    if (add2)
      __hip_atomic_fetch_add(add2, 1, __ATOMIC_RELAXED, __HIP_MEMORY_SCOPE_AGENT);
  }
}

__global__ __launch_bounds__(256, 1) void lstm_persist(
    const u32x4* __restrict__ xP, u16* __restrict__ h0P, u16* __restrict__ h1P,
    const float* __restrict__ Wih1, const float* __restrict__ Whh1,
    const float* __restrict__ Wih2, const float* __restrict__ Whh2,
    const float* __restrict__ bi1, const float* __restrict__ bh1,
    const float* __restrict__ bi2, const float* __restrict__ bh2,
    int* __restrict__ cnt0a, int* __restrict__ cnt0b, int* __restrict__ cnt1)
{
  __shared__ u32x4 sW[8192];                  // 128 KB
  const int tid = threadIdx.x;
  const int blk = blockIdx.x;
  const bool isL1 = (blk < 128);
  const int  lblk = isL1 ? blk : (blk - 128);
  const int  shard = lblk & 7;

  // ---- pack this block's weight slice fp32 -> bf16 LDS ----
  {
    const int nsec = isL1 ? 6144 : 8192;
    for (int i = tid; i < nsec; i += 256){
      int m = i & 15, grp_ = (i >> 4) & 3, T = (i >> 6) & 1, s = i >> 7;
      const float* W; int K, ks;
      if (isL1){
        if (s < 16){ W = Wih1; K = 512;  ks = s;      }
        else       { W = Whh1; K = 1024; ks = s - 16; }
      } else {
        if (s < 32){ W = Wih2; K = 1024; ks = s;      }
        else       { W = Whh2; K = 1024; ks = s - 32; }
      }
      int u = m >> 2, r = m & 3;
      const float* src = W + (size_t)(r*HID + lblk*8 + T*4 + u)*K + ks*32 + grp_*8;
      float4 a = *(const float4*)src;
      float4 c = *(const float4*)(src + 4);
      u32x4 o;
      o.x = pack2(a.x, a.y); o.y = pack2(a.z, a.w);
      o.z = pack2(c.x, c.y); o.w = pack2(c.z, c.w);
      sW[i] = o;
    }
  }

  const int w    = tid >> 6, l = tid & 63;
  const int grp  = l >> 4,  col = l & 15;
  const int b    = w*16 + col;
  const int aoff = l;
  const int boff = grp*64 + b;

  const int unitA = lblk*8 + grp;
  const int unitB = lblk*8 + 4 + grp;
  float bsA[4], bsB[4];
  #pragma unroll
  for (int r = 0; r < 4; ++r){
    if (isL1){
      bsA[r] = bi1[r*HID + unitA] + bh1[r*HID + unitA];
      bsB[r] = bi1[r*HID + unitB] + bh1[r*HID + unitB];
    } else {
      bsA[r] = bi2[r*HID + unitA] + bh2[r*HID + unitA];
      bsB[r] = bi2[r*HID + unitB] + bh2[r*HID + unitB];
    }
  }
  float cA = 0.f, cB = 0.f;
  const u32x4* h04 = (const u32x4*)h0P;
  const u32x4* h14 = (const u32x4*)h1P;
  __syncthreads();                            // weights visible; last barrier

  // counter word (u32 units): cnt + ((t*4 + w)*8 + shard)*32
  if (isL1){
    // ================= LAYER-1 blocks =================
    for (int t = 0; t < TX; ++t){
      f32x4 a00={0,0,0,0}, a01={0,0,0,0}, a10={0,0,0,0}, a11={0,0,0,0};
      // x-part first: cover for own-hop propagation
      {
        const u32x4* Bx = xP + (size_t)t*4096;
        #pragma unroll
        for (int s = 0; s < 16; s += 2){
          u32x4 B0 = Bx[s*256 + boff], B1 = Bx[(s+1)*256 + boff];
          MFMA(a00, sW[(s*2+0)*64 + aoff], B0);
          MFMA(a10, sW[(s*2+1)*64 + aoff], B0);
          MFMA(a01, sW[(s*2+2)*64 + aoff], B1);
          MFMA(a11, sW[(s*2+3)*64 + aoff], B1);
        }
      }
      if (t > 0) pollw(cnt0a + ((size_t)(t-1)*4 + w)*256);
      {
        const u32x4* Bh = h04 + (size_t)t*SLAB_V4;
        #pragma unroll
        for (int s = 0; s < 32; s += 2){
          u32x4 B0 = Bh[s*256 + boff], B1 = Bh[(s+1)*256 + boff];
          MFMA(a00, sW[((16+s)*2+0)*64 + aoff], B0);
          MFMA(a10, sW[((16+s)*2+1)*64 + aoff], B0);
          MFMA(a01, sW[((17+s)*2+0)*64 + aoff], B1);
          MFMA(a11, sW[((17+s)*2+1)*64 + aoff], B1);
        }
      }
      u32 m0 = cell_h(a00, a01, bsA, cA);
      u32 m1 = cell_h(a10, a11, bsB, cB);
      pub_store(h0P + (size_t)(t+1)*SLAB_U16 + (lblk<<9) + (w<<7), m0, m1);
      pub_signal(cnt0b + (((size_t)t*4 + w)*8 + shard)*32,   // L2 consumers first
                 cnt0a + (((size_t)t*4 + w)*8 + shard)*32);
    }
  } else {
    // ================= LAYER-2 blocks =================
    pollw(cnt0b + (size_t)(0*4 + w)*256);     // prologue: h0(1) ready?
    for (int t = 0; t < TX; ++t){
      f32x4 a00={0,0,0,0}, a01={0,0,0,0}, a10={0,0,0,0}, a11={0,0,0,0};
      // h0-part first (poll satisfied last iteration)
      {
        const u32x4* Bh = h04 + (size_t)(t+1)*SLAB_V4;
        #pragma unroll
        for (int s = 0; s < 32; s += 2){
          u32x4 B0 = Bh[s*256 + boff], B1 = Bh[(s+1)*256 + boff];
          MFMA(a00, sW[(s*2+0)*64 + aoff], B0);
          MFMA(a10, sW[(s*2+1)*64 + aoff], B0);
          MFMA(a01, sW[((s+1)*2+0)*64 + aoff], B1);
          MFMA(a11, sW[((s+1)*2+1)*64 + aoff], B1);
        }
      }
      // own-group hop had the whole h0-part to propagate
      if (t > 0) pollw(cnt1 + ((size_t)(t-1)*4 + w)*256);
      {
        const u32x4* Bh = h14 + (size_t)t*SLAB_V4;
        #pragma unroll
        for (int s = 0; s < 32; s += 2){
          u32x4 B0 = Bh[s*256 + boff], B1 = Bh[(s+1)*256 + boff];
          MFMA(a00, sW[((32+s)*2+0)*64 + aoff], B0);
          MFMA(a10, sW[((32+s)*2+1)*64 + aoff], B0);
          MFMA(a01, sW[((33+s)*2+0)*64 + aoff], B1);
          MFMA(a11, sW[((33+s)*2+1)*64 + aoff], B1);
        }
      }
      u32 m0 = cell_h(a00, a01, bsA, cA);
      u32 m1 = cell_h(a10, a11, bsB, cB);
      pub_store(h1P + (size_t)(t+1)*SLAB_U16 + (lblk<<9) + (w<<7), m0, m1);
      // hide next step's (satisfied) h0 poll under the store drain
      if (t + 1 < TX) pollw(cnt0b + ((size_t)(t+1)*4 + w)*256);
      pub_signal(cnt1 + (((size_t)t*4 + w)*8 + shard)*32, (int*)0);
    }
  }
}

// ---------------------------------------------------------------------------
// MFMA output projection with split-precision W_out (bf16 hi + bf16 lo).
// ---------------------------------------------------------------------------
__global__ __launch_bounds__(256, 1) void out_gemm(
    const u16* __restrict__ h1P, const float* __restrict__ W_out,
    const float* __restrict__ b_out, float* __restrict__ out)
{
  __shared__ u32x4 sA[8192];                  // 128 KB (A hi/lo chunk; C reuse)
  const int tid = threadIdx.x, l = tid & 63, w = tid >> 6;
  const int grp = l >> 4, col = l & 15;
  const int b   = w*16 + col;
  const int vbase = blockIdx.x * 128;
  const int t0    = blockIdx.y * 4;

  f32x4 acc0[8], acc1[8], acc2[8], acc3[8];
  #pragma unroll
  for (int m = 0; m < 8; ++m){
    acc0[m]=(f32x4){0,0,0,0}; acc1[m]=(f32x4){0,0,0,0};
    acc2[m]=(f32x4){0,0,0,0}; acc3[m]=(f32x4){0,0,0,0};
  }
  const u32x4* h14 = (const u32x4*)h1P;

  for (int kc = 0; kc < 4; ++kc){
    __syncthreads();
    #pragma unroll
    for (int k = 0; k < 16; ++k){
      int j = tid + k*256;
      int lane = j & 63, mt = (j >> 6) & 7, s = j >> 9;
      int v  = vbase + mt*16 + (lane & 15);
      int kk = kc*256 + s*32 + (lane >> 4)*8;
      const float* src = W_out + (size_t)v*HID + kk;
      float4 f0 = *(const float4*)src, f1 = *(const float4*)(src + 4);
      float e[8] = {f0.x,f0.y,f0.z,f0.w,f1.x,f1.y,f1.z,f1.w};
      u16 hi[8]; float lo[8];
      #pragma unroll
      for (int r = 0; r < 8; ++r){ hi[r] = f2bf(e[r]); lo[r] = e[r] - bf2f(hi[r]); }
      u32x4 H, L;
      H.x = (u32)hi[0]|((u32)hi[1]<<16); H.y = (u32)hi[2]|((u32)hi[3]<<16);
      H.z = (u32)hi[4]|((u32)hi[5]<<16); H.w = (u32)hi[6]|((u32)hi[7]<<16);
      L.x = pack2(lo[0],lo[1]); L.y = pack2(lo[2],lo[3]);
      L.z = pack2(lo[4],lo[5]); L.w = pack2(lo[6],lo[7]);
      int base = (s*8 + mt)*128 + lane;
      sA[base]      = H;
      sA[base + 64] = L;
    }
    __syncthreads();

    #pragma unroll
    for (int s = 0; s < 8; ++s){
      int ksl = kc*8 + s;
      int bi  = ksl*256 + grp*64 + b;
      u32x4 B0 = h14[(size_t)(t0+1)*SLAB_V4 + bi];
      u32x4 B1 = h14[(size_t)(t0+2)*SLAB_V4 + bi];
      u32x4 B2 = h14[(size_t)(t0+3)*SLAB_V4 + bi];
      u32x4 B3 = h14[(size_t)(t0+4)*SLAB_V4 + bi];
      #pragma unroll
      for (int mt = 0; mt < 8; ++mt){
        u32x4 Ah = sA[(s*8 + mt)*128 + l];
        u32x4 Al = sA[(s*8 + mt)*128 + 64 + l];
        MFMA(acc0[mt], Ah, B0); MFMA(acc1[mt], Ah, B1);
        MFMA(acc2[mt], Ah, B2); MFMA(acc3[mt], Ah, B3);
        MFMA(acc0[mt], Al, B0); MFMA(acc1[mt], Al, B1);
        MFMA(acc2[mt], Al, B2); MFMA(acc3[mt], Al, B3);
      }
    }
  }

  float* sC = (float*)sA;                     // [64][132] fp32
#define EPILOGUE(ACC, TT)                                                       \
  {                                                                             \
    __syncthreads();                                                            \
    _Pragma("unroll")                                                           \
    for (int mt = 0; mt < 8; ++mt){                                             \
      f32x4 a = ACC[mt];                                                        \
      _Pragma("unroll")                                                         \
      for (int r = 0; r < 4; ++r)                                               \
        sC[b*132 + mt*16 + grp*4 + r] = a[r];                                   \
    }                                                                           \
    __syncthreads();                                                            \
    {                                                                           \
      int bb = tid >> 2, q = tid & 3;                                           \
      const float* cp = sC + bb*132 + q*32;                                     \
      const float* bo = b_out + vbase + q*32;                                   \
      float* op = out + ((size_t)(t0+TT)*BATCH + bb)*VOCAB + vbase + q*32;      \
      _Pragma("unroll")                                                         \
      for (int j = 0; j < 8; ++j){                                              \
        float4 cv = *(const float4*)(cp + j*4);                                 \
        float4 bv = *(const float4*)(bo + j*4);                                 \
        float4 ov = {cv.x+bv.x, cv.y+bv.y, cv.z+bv.z, cv.w+bv.w};               \
        *(float4*)(op + j*4) = ov;                                              \
      }                                                                         \
    }                                                                           \
  }
  EPILOGUE(acc0, 0)
  EPILOGUE(acc1, 1)
  EPILOGUE(acc2, 2)
  EPILOGUE(acc3, 3)
#undef EPILOGUE
}

// ---------------------------------------------------------------------------
extern "C" void kernel_launch(void* const* d_in, const int* in_sizes, int n_in,
                              void* d_out, int out_size, void* d_ws, size_t ws_size,
                              hipStream_t stream)
{
  const int*   x     = (const int*)  d_in[0];
  const float* emb   = (const float*)d_in[1];
  const float* W_ih1 = (const float*)d_in[2];
  const float* W_hh1 = (const float*)d_in[3];
  const float* b_ih1 = (const float*)d_in[4];
  const float* b_hh1 = (const float*)d_in[5];
  const float* W_ih2 = (const float*)d_in[6];
  const float* W_hh2 = (const float*)d_in[7];
  const float* b_ih2 = (const float*)d_in[8];
  const float* b_hh2 = (const float*)d_in[9];
  const float* W_out = (const float*)d_in[10];
  const float* b_out = (const float*)d_in[11];
  float* out = (float*)d_out;

  char* ws = (char*)d_ws;
  int*   cnt0a = (int*)  (ws + OFF_CNT0A);
  int*   cnt0b = (int*)  (ws + OFF_CNT0B);
  int*   cnt1  = (int*)  (ws + OFF_CNT1);
  u16*   h0P   = (u16*)  (ws + OFF_H0);
  u16*   h1P   = (u16*)  (ws + OFF_H1);
  u32x4* xP    = (u32x4*)(ws + OFF_XP);

  hipMemsetAsync(ws, 0, 3145728, stream);              // all counters
  hipMemsetAsync(ws + OFF_H0, 0, 131072, stream);      // h0 slab 0 = zeros
  hipMemsetAsync(ws + OFF_H1, 0, 131072, stream);      // h1 slab 0 = zeros

  embed_pack<<<4096, 256, 0, stream>>>(x, emb, xP);

  lstm_persist<<<256, 256, 0, stream>>>(
      xP, h0P, h1P, W_ih1, W_hh1, W_ih2, W_hh2,
      b_ih1, b_hh1, b_ih2, b_hh2, cnt0a, cnt0b, cnt1);

  dim3 og(VOCAB/128, TX/4);
  out_gemm<<<og, 256, 0, stream>>>(h1P, W_out, b_out, out);
}